// Round 11
// baseline (290.844 us; speedup 1.0000x reference)
//
#include <hip/hip_runtime.h>
#include <hip/hip_bf16.h>
#include <stdint.h>

#define T_TOK 4096
#define DD 1024
#define EE 8
#define CC 512
#define FF 2752

typedef __attribute__((ext_vector_type(8))) short bf16x8;
typedef __attribute__((ext_vector_type(4))) float f32x4;
typedef __attribute__((ext_vector_type(4))) unsigned short us4;
typedef __attribute__((ext_vector_type(8))) unsigned short us8;

__device__ __forceinline__ float bf2f(unsigned short u) {
  union { float f; unsigned int i; } v; v.i = ((unsigned int)u) << 16; return v.f;
}
__device__ __forceinline__ unsigned short f2bf(float f) {
  union { float f; unsigned int i; } v; v.f = f;
  unsigned int r = v.i + 0x7fffu + ((v.i >> 16) & 1u);
  return (unsigned short)(r >> 16);
}

#define GLDS16(g, l) __builtin_amdgcn_global_load_lds( \
    (const __attribute__((address_space(1))) void*)(g), \
    (__attribute__((address_space(3))) void*)(l), 16, 0, 0)

// Verified swizzle (rounds 3-10) for A (glds-staged bf16 fragments).
#define STG_CHUNK(l) (((l & 3) ^ ((l >> 3) & 3)) * 8)
#define RD_OFF(fr, fq) ((fr) * 32 + (((fq) ^ (((fr) >> 1) & 3)) * 8))

#define BAR() do { asm volatile("" ::: "memory"); __builtin_amdgcn_s_barrier(); \
                   asm volatile("" ::: "memory"); } while (0)

// ---------------- weight transpose + f32->bf16 (w2 only) ---------
template<int RT>
__global__ __launch_bounds__(256)
void transpose_k(const float* __restrict__ in, const float* __restrict__ in2,
                 unsigned short* __restrict__ out, unsigned short* __restrict__ out2,
                 int R, int C, long inStride, long outStride) {
  __shared__ unsigned short sm[RT * 64];
  int b = blockIdx.z;
  if (b < EE) { in += (long)b * inStride; out += (long)b * outStride; }
  else { in = in2; out = out2; }
  int cb = blockIdx.x * 64, rb = blockIdx.y * RT;
  int t = threadIdx.x;
  int rr = t >> 4, c4 = (t & 15) * 4;
#pragma unroll
  for (int i = 0; i < RT / 16; ++i) {
    int r = rr + i * 16;
    float4 v = *(const float4*)(in + (long)(rb + r) * C + cb + c4);
    us4 o; o.x = f2bf(v.x); o.y = f2bf(v.y); o.z = f2bf(v.z); o.w = f2bf(v.w);
    *(us4*)&sm[r * 64 + (c4 ^ (((r >> 3) & 7) << 3))] = o;
  }
  __syncthreads();
#pragma unroll
  for (int j = 0; j < (64 * (RT / 8)) / 256; ++j) {
    int idx = t + j * 256;
    int g, c;
    if (RT == 128) { g = idx & 15; c = idx >> 4; }
    else           { g = idx & 7;  c = idx >> 3; }
    int r8 = g * 8;
    us8 o;
#pragma unroll
    for (int k = 0; k < 8; ++k) {
      int r = r8 + k;
      o[k] = sm[r * 64 + (c ^ (((r >> 3) & 7) << 3))];
    }
    *(us8*)(out + (long)(cb + c) * R + rb + r8) = o;
  }
}

__global__ void zero_me_k(float* me) { if (threadIdx.x < EE) me[threadIdx.x] = 0.0f; }

// ---------------- gating ----------------
__global__ void gate_k(const float* __restrict__ x, const float* __restrict__ wg,
                       const float* __restrict__ cw, const float* __restrict__ cbv,
                       int* __restrict__ idx, float* __restrict__ gatev,
                       float* __restrict__ coef, float* __restrict__ me_sum) {
  int tid = threadIdx.x, lane = tid & 63, wv = tid >> 6;
  int t = blockIdx.x * 4 + wv;
  const float* xr = x + (long)t * DD;
  float acc[EE] = {0,0,0,0,0,0,0,0};
  float c0 = 0.0f, c1 = 0.0f;
  for (int d = lane; d < DD; d += 64) {
    float xv = xr[d];
#pragma unroll
    for (int e = 0; e < EE; ++e) acc[e] += xv * wg[d * EE + e];
    c0 += xv * cw[d * 2 + 0];
    c1 += xv * cw[d * 2 + 1];
  }
#pragma unroll
  for (int o = 32; o > 0; o >>= 1) {
#pragma unroll
    for (int e = 0; e < EE; ++e) acc[e] += __shfl_xor(acc[e], o);
    c0 += __shfl_xor(c0, o);
    c1 += __shfl_xor(c1, o);
  }
  __shared__ float sme[EE];
  if (tid < EE) sme[tid] = 0.0f;
  __syncthreads();
  if (lane == 0) {
    float m = acc[0]; int am = 0;
#pragma unroll
    for (int e = 1; e < EE; ++e) if (acc[e] > m) { m = acc[e]; am = e; }
    float g[EE]; float s = 0.0f;
#pragma unroll
    for (int e = 0; e < EE; ++e) { g[e] = __expf(acc[e] - m); s += g[e]; }
    float inv = 1.0f / s;
    idx[t] = am;
    gatev[t] = g[am] * inv;
#pragma unroll
    for (int e = 0; e < EE; ++e) atomicAdd(&sme[e], g[e] * inv);
    float l0 = c0 + cbv[0], l1 = c1 + cbv[1];
    float mm = fmaxf(l0, l1);
    float e0 = __expf(l0 - mm), e1 = __expf(l1 - mm);
    float is = 1.0f / (e0 + e1);
    coef[t * 2 + 0] = e0 * is;
    coef[t * 2 + 1] = e1 * is;
  }
  __syncthreads();
  if (tid < EE) atomicAdd(&me_sum[tid], sme[tid]);
}

// ---------------- capacity scan ----------------
__global__ void scan_k(const int* __restrict__ idx, const float* __restrict__ me_sum,
                       int* __restrict__ slot, int* __restrict__ tok,
                       float* __restrict__ out_tail) {
  __shared__ int sidx[T_TOK];
  __shared__ int counts[EE];
  int tid = threadIdx.x;
  for (int i = tid; i < T_TOK; i += 512) sidx[i] = idx[i];
  __syncthreads();
  int e = tid >> 6, lane = tid & 63;
  int base = 0;
  for (int it = 0; it < T_TOK / 64; ++it) {
    int t = it * 64 + lane;
    bool f = (sidx[t] == e);
    unsigned long long m = __ballot(f);
    if (f) {
      int loc = base + __popcll(m & ((1ull << lane) - 1ull));
      slot[t] = (loc < CC) ? loc : -1;
      if (loc < CC) tok[e * CC + loc] = t;
    }
    base += __popcll(m);
  }
  if (lane == 0) counts[e] = base;
  __syncthreads();
  int filled = min(counts[e], CC);
  for (int c = filled + lane; c < CC; c += 64) tok[e * CC + c] = -1;
  if (tid == 0) {
    float la = 0.0f;
    for (int i = 0; i < EE; ++i) la += me_sum[i] * (float)counts[i];
    la *= (float)EE / ((float)T_TOK * (float)T_TOK);
    out_tail[0] = la;
    for (int i = 0; i < EE; ++i) out_tail[1 + i] = (float)counts[i];
  }
}

// ---------------- gather + bf16 convert ----------------
__global__ void gather_k(const float* __restrict__ x, const int* __restrict__ tok,
                         unsigned short* __restrict__ xb, unsigned short* __restrict__ xe) {
  int r = blockIdx.x, tid = threadIdx.x;
  int d = tid * 4;
  if (r < T_TOK) {
    float4 v = *(const float4*)(x + (long)r * DD + d);
    us4 o; o.x = f2bf(v.x); o.y = f2bf(v.y); o.z = f2bf(v.z); o.w = f2bf(v.w);
    *(us4*)(xb + (long)r * DD + d) = o;
  } else {
    int s = r - T_TOK;
    int t = tok[s];
    us4 o = {0, 0, 0, 0};
    if (t >= 0) {
      float4 v = *(const float4*)(x + (long)t * DD + d);
      o.x = f2bf(v.x); o.y = f2bf(v.y); o.z = f2bf(v.z); o.w = f2bf(v.w);
    }
    *(us4*)(xe + (long)s * DD + d) = o;
  }
}

// ---------------- GEMM1: H = silu(A@W1)*(A@W3) -------------------
// f32 weights consumed directly; B register-staged: coalesced float4 loads
// (lane = rows k,k+1 x 4n) -> v_cvt_pk_bf16_f32 -> ds_write_b32 into a bf16
// fragment-ordered B layout with B-specific XOR (reads 2-way free, writes
// 4-way). 3 buffers, 1 barrier/half, loads for h+2 issued at h (T14),
// vmcnt(6) drains [Bld(h+1) x4, Agld(h+1) x2] each iter (queue-accounted).
__global__ __launch_bounds__(512, 2)
void gemm1_k(const unsigned short* __restrict__ xcat,
             const float* __restrict__ w1, const float* __restrict__ w3,
             const float* __restrict__ rw1, const float* __restrict__ rw3,
             unsigned short* __restrict__ Hcat) {
  int lin = blockIdx.x;
  int work = (lin & 7) * 88 + (lin >> 3);     // 704 = 8 * 88
  int mtile, ntile;
  if (work < 352) {            // experts: B-panel-sharing mtile pair adjacent
    int e = work / 44, r = work - e * 44;
    ntile = r >> 1;
    mtile = e * 2 + (r & 1);
  } else {                     // residual: 16 consecutive share B panel
    int q = work - 352;
    ntile = q >> 4;
    mtile = 16 + (q & 15);
  }
  const unsigned short* A = xcat + (size_t)mtile * 256 * DD;
  const float *B1, *B3;
  if (mtile < 16) { int e = mtile >> 1; B1 = w1 + (size_t)e * DD * FF; B3 = w3 + (size_t)e * DD * FF; }
  else { B1 = rw1; B3 = rw3; }
  unsigned short* H = Hcat + (size_t)mtile * 256 * FF;
  int n0 = ntile * 128;

  __shared__ __align__(16) char Lc[98304];   // 96 KB
  // A:  3 bufs x 16KB [0..49152)
  // B1: 3 bufs x 8KB  [49152..73728)
  // B3: 3 bufs x 8KB  [73728..98304)

  int tid = threadIdx.x, l = tid & 63, w = tid >> 6;
  int wm = w >> 1, wn = w & 1;
  int fr = l & 15, fq = l >> 4;
  int srow = l >> 2, soff = STG_CHUNK(l);
  int rdo2 = RD_OFF(fr, fq) * 2;             // A-frag byte offset

  // B-frag read: byte(g) = (g*1024 + chB) ^ ((g&1)<<6), chB = fr*64 + chunkB*16
  int chB = fr * 64 + ((fq ^ ((fr >> 1) & 3) ^ ((fr >> 2) & 3)) * 16);

  // A staging sources
  const unsigned short* gA0 = A + (size_t)(w * 16 + srow) * DD + soff;
  const unsigned short* gA1 = A + (size_t)((8 + w) * 16 + srow) * DD + soff;

  // B load mapping: lane = rows (w*4+kp*2, +1), cols n0 + c*4 .. +3
  int kp = l >> 5, c = l & 31;
  int nn = n0 + c * 4; if (nn >= FF) nn = 0;   // clamp OOB (epilogue masks)
  const float* pB1 = B1 + (size_t)(w * 4 + kp * 2) * FF + nn;
  const float* pB3 = B3 + (size_t)(w * 4 + kp * 2) * FF + nn;

  // B write offsets (4 per lane, b32 each covering k,k+1)
  int fq_w = w >> 1, j_w = (w & 1) * 4 + kp * 2;
  int frg = c >> 2;
  int wboff[4];
#pragma unroll
  for (int i = 0; i < 4; ++i) {
    int frw = 4 * (c & 3) + i;
    int chw = fq_w ^ ((frw >> 1) & 3) ^ ((frw >> 2) & 3);
    wboff[i] = (frg * 1024 + frw * 64 + chw * 16 + j_w * 2) ^ ((frg & 1) << 6);
  }

  auto agld = [&](int bb, int hw) {
    size_t ka = (size_t)hw * 32;
    GLDS16(gA0 + ka, Lc + bb * 16384 + w * 1024);
    GLDS16(gA1 + ka, Lc + bb * 16384 + (8 + w) * 1024);
  };
  auto bload = [&](int hw, float4& ra, float4& rb, float4& rc, float4& rd) {
    size_t kb = (size_t)hw * 32 * FF;
    ra = *(const float4*)(pB1 + kb);
    rb = *(const float4*)(pB1 + kb + FF);
    rc = *(const float4*)(pB3 + kb);
    rd = *(const float4*)(pB3 + kb + FF);
  };
  auto bwrite = [&](int bb, float4& ra, float4& rb, float4& rc, float4& rd) {
    char* b1d = Lc + 49152 + bb * 8192;
    char* b3d = Lc + 73728 + bb * 8192;
    const float* fa = (const float*)&ra; const float* fb = (const float*)&rb;
    const float* fc = (const float*)&rc; const float* fd = (const float*)&rd;
#pragma unroll
    for (int i = 0; i < 4; ++i) {
      unsigned int u;
      asm("v_cvt_pk_bf16_f32 %0, %1, %2" : "=v"(u) : "v"(fa[i]), "v"(fb[i]));
      *(unsigned int*)(b1d + wboff[i]) = u;
    }
#pragma unroll
    for (int i = 0; i < 4; ++i) {
      unsigned int u;
      asm("v_cvt_pk_bf16_f32 %0, %1, %2" : "=v"(u) : "v"(fc[i]), "v"(fd[i]));
      *(unsigned int*)(b3d + wboff[i]) = u;
    }
  };

  f32x4 acc1[4][4] = {};
  f32x4 acc3[4][4] = {};
  bf16x8 af[4], bfB[4];

  auto readA = [&](int bb) {
#pragma unroll
    for (int mi = 0; mi < 4; ++mi)
      af[mi] = *(const bf16x8*)(Lc + bb * 16384 + (wm * 4 + mi) * 1024 + rdo2);
  };
  auto readB = [&](int rbase, int bb) {
#pragma unroll
    for (int ni = 0; ni < 4; ++ni) {
      int g = wn * 4 + ni;
      bfB[ni] = *(const bf16x8*)(Lc + rbase + bb * 8192 + ((g * 1024 + chB) ^ ((g & 1) << 6)));
    }
  };
  auto mm1 = [&]() {
    __builtin_amdgcn_s_setprio(1);
#pragma unroll
    for (int mi = 0; mi < 4; ++mi)
#pragma unroll
      for (int ni = 0; ni < 4; ++ni)
        acc1[mi][ni] = __builtin_amdgcn_mfma_f32_16x16x32_bf16(af[mi], bfB[ni], acc1[mi][ni], 0, 0, 0);
    __builtin_amdgcn_s_setprio(0);
  };
  auto mm3 = [&]() {
    __builtin_amdgcn_s_setprio(1);
#pragma unroll
    for (int mi = 0; mi < 4; ++mi)
#pragma unroll
      for (int ni = 0; ni < 4; ++ni)
        acc3[mi][ni] = __builtin_amdgcn_mfma_f32_16x16x32_bf16(af[mi], bfB[ni], acc3[mi][ni], 0, 0, 0);
    __builtin_amdgcn_s_setprio(0);
  };

  float4 s0a, s0b, s0c, s0d, s1a, s1b, s1c, s1d;
  const int HN = 32;   // K halves (1024/32)

  // prologue: queue = [Bld(0) 4, Agld(0) 2, Bld(1) 4, Agld(1) 2]
  bload(0, s0a, s0b, s0c, s0d);
  agld(0, 0);
  bload(1, s1a, s1b, s1c, s1d);
  agld(1, 1);
  asm volatile("s_waitcnt vmcnt(8)" ::: "memory");   // Bld(0) landed
  bwrite(0, s0a, s0b, s0c, s0d);
  asm volatile("s_waitcnt vmcnt(6)" ::: "memory");   // Agld(0) landed
  asm volatile("s_waitcnt lgkmcnt(0)" ::: "memory"); // B(0) writes visible

#pragma unroll 2
  for (int h = 0; h < HN; ++h) {
    int buf = h % 3;
    int buf1 = (h + 1) % 3;
    int hw2 = h + 2; if (hw2 >= HN) hw2 -= HN;
    int buf2 = hw2 % 3;

    BAR();                       // buffer `buf` complete for all waves
    readA(buf);
    readB(49152, buf);
    if ((h & 1) == 0) bload(hw2, s0a, s0b, s0c, s0d);
    else              bload(hw2, s1a, s1b, s1c, s1d);
    agld(buf2, hw2);
    mm1();
    readB(73728, buf);
    mm3();
    asm volatile("s_waitcnt vmcnt(6)" ::: "memory");  // drains Bld(h+1)+Agld(h+1)
    if ((h & 1) == 0) bwrite(buf1, s1a, s1b, s1c, s1d);
    else              bwrite(buf1, s0a, s0b, s0c, s0d);
    asm volatile("s_waitcnt lgkmcnt(0)" ::: "memory");
  }

#pragma unroll
  for (int mi = 0; mi < 4; ++mi)
#pragma unroll
    for (int ni = 0; ni < 4; ++ni)
#pragma unroll
      for (int r = 0; r < 4; ++r) {
        int gm = wm * 64 + mi * 16 + fq * 4 + r;
        int gn = n0 + wn * 64 + ni * 16 + fr;
        if (gn < FF) {
          float v1 = acc1[mi][ni][r], v3 = acc3[mi][ni][r];
          float h = v1 / (1.0f + __expf(-v1)) * v3;
          H[(size_t)gm * FF + gn] = f2bf(h);
        }
      }
}

// ---------------- GEMM2: Y = H @ W2 (round-9/10 verified) --------
__global__ __launch_bounds__(512, 2)
void gemm2_k(const unsigned short* __restrict__ Hcat,
             const unsigned short* __restrict__ w2t, const unsigned short* __restrict__ rw2t,
             unsigned short* __restrict__ Ycat) {
  int lin = blockIdx.x;
  int work = (lin & 7) * 32 + (lin >> 3);    // 256 = 8 * 32
  int mtile, ntile;
  if (work < 128) {
    int e = work >> 4, r = work & 15;
    ntile = r >> 1;
    mtile = e * 2 + (r & 1);
  } else {
    int q = work - 128;
    ntile = q >> 4;
    mtile = 16 + (q & 15);
  }
  const unsigned short* A = Hcat + (size_t)mtile * 256 * FF;
  const unsigned short* B = (mtile < 16) ? (w2t + (size_t)(mtile >> 1) * (size_t)DD * FF) : rw2t;
  unsigned short* Y = Ycat + (size_t)mtile * 256 * DD;
  int n0 = ntile * 128;

  __shared__ __align__(16) unsigned short lds[73728];   // 144 KB
  char* Lc = (char*)lds;

  int tid = threadIdx.x, l = tid & 63, w = tid >> 6;
  int wm = w >> 1, wn = w & 1;
  int fr = l & 15, fq = l >> 4;
  int srow = l >> 2, soff = STG_CHUNK(l);
  int rdo = RD_OFF(fr, fq);

  const unsigned short* gA0 = A + (size_t)(w * 16 + srow) * FF + soff;
  const unsigned short* gA1 = A + (size_t)((8 + w) * 16 + srow) * FF + soff;
  const unsigned short* gB  = B + (size_t)(n0 + w * 16 + srow) * FF + soff;

#define STG2(bb, kk) do {                                          \
    GLDS16(gA0 + (kk), Lc + (bb) * 16384 + w * 1024);              \
    GLDS16(gA1 + (kk), Lc + (bb) * 16384 + (8 + w) * 1024);        \
    GLDS16(gB  + (kk), Lc + 98304 + (bb) * 8192 + w * 1024); } while (0)

  f32x4 acc[4][4] = {};

  const int HN = 86;   // halves (K=2752 / 32)
#pragma unroll
  for (int hh = 0; hh < 5; ++hh) STG2(hh, hh * 32);
  asm volatile("s_waitcnt vmcnt(12)" ::: "memory");
  BAR();

  int b = 0;
#pragma unroll 2
  for (int h = 0; h < HN; ++h) {
    int bn = b ? b - 1 : 5;              // (h+5) % 6
    int hw = h + 5; if (hw >= HN) hw -= HN;
    int kk = hw * 32;
    bf16x8 af[4], bf[4];

#pragma unroll
    for (int mi = 0; mi < 4; ++mi)
      af[mi] = *(const bf16x8*)(lds + b * 8192 + (wm * 4 + mi) * 512 + rdo);
#pragma unroll
    for (int ni = 0; ni < 4; ++ni)
      bf[ni] = *(const bf16x8*)(lds + 49152 + b * 4096 + (wn * 4 + ni) * 512 + rdo);
    STG2(bn, kk);
    asm volatile("s_waitcnt vmcnt(12)" ::: "memory");
    BAR();
    __builtin_amdgcn_s_setprio(1);
#pragma unroll
    for (int mi = 0; mi < 4; ++mi)
#pragma unroll
      for (int ni = 0; ni < 4; ++ni)
        acc[mi][ni] = __builtin_amdgcn_mfma_f32_16x16x32_bf16(af[mi], bf[ni], acc[mi][ni], 0, 0, 0);
    __builtin_amdgcn_s_setprio(0);
    BAR();

    ++b; if (b == 6) b = 0;
  }
#undef STG2

#pragma unroll
  for (int mi = 0; mi < 4; ++mi)
#pragma unroll
    for (int ni = 0; ni < 4; ++ni)
#pragma unroll
      for (int r = 0; r < 4; ++r) {
        int gm = wm * 64 + mi * 16 + fq * 4 + r;
        int gn = n0 + wn * 64 + ni * 16 + fr;
        Y[(size_t)gm * DD + gn] = f2bf(acc[mi][ni][r]);
      }
}

// ---------------- combine ----------------------------------------
__global__ void combine_k(const unsigned short* __restrict__ Ye, const unsigned short* __restrict__ Yr,
                          const int* __restrict__ idx, const int* __restrict__ slot,
                          const float* __restrict__ gatev, const float* __restrict__ coef,
                          float* __restrict__ out) {
  int t = blockIdx.x, tid = threadIdx.x;
  int d = tid * 4;
  float c0 = coef[t * 2], c1 = coef[t * 2 + 1];
  int s = slot[t];
  float g = gatev[t] * c0;
  us4 vr = *(const us4*)(Yr + (size_t)t * DD + d);
  float4 o;
  if (s >= 0) {
    us4 ve = *(const us4*)(Ye + ((size_t)idx[t] * CC + s) * DD + d);
    o.x = g * bf2f(ve.x) + c1 * bf2f(vr.x);
    o.y = g * bf2f(ve.y) + c1 * bf2f(vr.y);
    o.z = g * bf2f(ve.z) + c1 * bf2f(vr.z);
    o.w = g * bf2f(ve.w) + c1 * bf2f(vr.w);
  } else {
    o.x = c1 * bf2f(vr.x);
    o.y = c1 * bf2f(vr.y);
    o.z = c1 * bf2f(vr.z);
    o.w = c1 * bf2f(vr.w);
  }
  *(float4*)(out + (size_t)t * DD + d) = o;
}

// ---------------- launch -----------------------------------------
extern "C" void kernel_launch(void* const* d_in, const int* in_sizes, int n_in,
                              void* d_out, int out_size, void* d_ws, size_t ws_size,
                              hipStream_t stream) {
  const float* x   = (const float*)d_in[0];
  const float* wg  = (const float*)d_in[1];
  const float* w1  = (const float*)d_in[2];
  const float* w3  = (const float*)d_in[3];
  const float* w2  = (const float*)d_in[4];
  const float* rw1 = (const float*)d_in[5];
  const float* rw3 = (const float*)d_in[6];
  const float* rw2 = (const float*)d_in[7];
  const float* cw  = (const float*)d_in[8];
  const float* cbv = (const float*)d_in[9];
  float* out = (float*)d_out;

  char* ws = (char*)d_ws;
  size_t o = 0;
  auto alloc = [&](size_t bytes) -> char* {
    char* p = ws + o; o = (o + bytes + 255) & ~(size_t)255; return p;
  };
  unsigned short* w2t  = (unsigned short*)alloc((size_t)EE * DD * FF * 2);
  unsigned short* rw2t = (unsigned short*)alloc((size_t)DD * FF * 2);
  // contiguous pairs: xe|xb, He|Hr, Ye|Yr
  unsigned short* xe   = (unsigned short*)alloc((size_t)T_TOK * DD * 2);
  unsigned short* xb   = (unsigned short*)alloc((size_t)T_TOK * DD * 2);
  unsigned short* He   = (unsigned short*)alloc((size_t)T_TOK * FF * 2);
  unsigned short* Hr   = (unsigned short*)alloc((size_t)T_TOK * FF * 2);
  unsigned short* Ye   = (unsigned short*)alloc((size_t)T_TOK * DD * 2);
  unsigned short* Yr   = (unsigned short*)alloc((size_t)T_TOK * DD * 2);
  int*   idxp  = (int*)alloc(T_TOK * 4);
  float* gatev = (float*)alloc(T_TOK * 4);
  int*   slotp = (int*)alloc(T_TOK * 4);
  int*   tokp  = (int*)alloc(EE * CC * 4);
  float* coefp = (float*)alloc(T_TOK * 2 * 4);
  float* mep   = (float*)alloc(256);
  if (o > ws_size) return;

  // only w2 needs the transpose+convert pre-pass
  transpose_k<64><<<dim3(16, 43, EE + 1), 256, 0, stream>>>(w2, rw2, w2t, rw2t, FF, DD, (long)FF * DD, (long)DD * FF);

  zero_me_k<<<1, 64, 0, stream>>>(mep);
  gate_k<<<T_TOK / 4, 256, 0, stream>>>(x, wg, cw, cbv, idxp, gatev, coefp, mep);
  scan_k<<<1, 512, 0, stream>>>(idxp, mep, slotp, tokp, out + (size_t)T_TOK * DD);
  gather_k<<<2 * T_TOK, 256, 0, stream>>>(x, tokp, xb, xe);
  gemm1_k<<<704, 512, 0, stream>>>(xe, w1, w3, rw1, rw3, He);
  gemm2_k<<<256, 512, 0, stream>>>(He, w2t, rw2t, Ye);
  combine_k<<<T_TOK, 256, 0, stream>>>(Ye, Yr, idxp, slotp, gatev, coefp, out);
}

// Round 12
// 266.075 us; speedup vs baseline: 1.0931x; 1.0931x over previous
//
#include <hip/hip_runtime.h>
#include <hip/hip_bf16.h>
#include <stdint.h>

#define T_TOK 4096
#define DD 1024
#define EE 8
#define CC 512
#define FF 2752

typedef __attribute__((ext_vector_type(8))) short bf16x8;
typedef __attribute__((ext_vector_type(4))) float f32x4;
typedef __attribute__((ext_vector_type(4))) unsigned short us4;
typedef __attribute__((ext_vector_type(8))) unsigned short us8;

__device__ __forceinline__ float bf2f(unsigned short u) {
  union { float f; unsigned int i; } v; v.i = ((unsigned int)u) << 16; return v.f;
}
__device__ __forceinline__ unsigned short f2bf(float f) {
  union { float f; unsigned int i; } v; v.f = f;
  unsigned int r = v.i + 0x7fffu + ((v.i >> 16) & 1u);
  return (unsigned short)(r >> 16);
}

#define GLDS16(g, l) __builtin_amdgcn_global_load_lds( \
    (const __attribute__((address_space(1))) void*)(g), \
    (__attribute__((address_space(3))) void*)(l), 16, 0, 0)

// Verified swizzle (rounds 3-10) for A (glds-staged bf16 fragments).
#define STG_CHUNK(l) (((l & 3) ^ ((l >> 3) & 3)) * 8)
#define RD_OFF(fr, fq) ((fr) * 32 + (((fq) ^ (((fr) >> 1) & 3)) * 8))

#define BAR() do { asm volatile("" ::: "memory"); __builtin_amdgcn_s_barrier(); \
                   asm volatile("" ::: "memory"); } while (0)

// ---------------- weight transpose + f32->bf16 (w2 only) ---------
template<int RT>
__global__ __launch_bounds__(256)
void transpose_k(const float* __restrict__ in, const float* __restrict__ in2,
                 unsigned short* __restrict__ out, unsigned short* __restrict__ out2,
                 int R, int C, long inStride, long outStride) {
  __shared__ unsigned short sm[RT * 64];
  int b = blockIdx.z;
  if (b < EE) { in += (long)b * inStride; out += (long)b * outStride; }
  else { in = in2; out = out2; }
  int cb = blockIdx.x * 64, rb = blockIdx.y * RT;
  int t = threadIdx.x;
  int rr = t >> 4, c4 = (t & 15) * 4;
#pragma unroll
  for (int i = 0; i < RT / 16; ++i) {
    int r = rr + i * 16;
    float4 v = *(const float4*)(in + (long)(rb + r) * C + cb + c4);
    us4 o; o.x = f2bf(v.x); o.y = f2bf(v.y); o.z = f2bf(v.z); o.w = f2bf(v.w);
    *(us4*)&sm[r * 64 + (c4 ^ (((r >> 3) & 7) << 3))] = o;
  }
  __syncthreads();
#pragma unroll
  for (int j = 0; j < (64 * (RT / 8)) / 256; ++j) {
    int idx = t + j * 256;
    int g, c;
    if (RT == 128) { g = idx & 15; c = idx >> 4; }
    else           { g = idx & 7;  c = idx >> 3; }
    int r8 = g * 8;
    us8 o;
#pragma unroll
    for (int k = 0; k < 8; ++k) {
      int r = r8 + k;
      o[k] = sm[r * 64 + (c ^ (((r >> 3) & 7) << 3))];
    }
    *(us8*)(out + (long)(cb + c) * R + rb + r8) = o;
  }
}

__global__ void zero_me_k(float* me) { if (threadIdx.x < EE) me[threadIdx.x] = 0.0f; }

// ---------------- gating ----------------
__global__ void gate_k(const float* __restrict__ x, const float* __restrict__ wg,
                       const float* __restrict__ cw, const float* __restrict__ cbv,
                       int* __restrict__ idx, float* __restrict__ gatev,
                       float* __restrict__ coef, float* __restrict__ me_sum) {
  int tid = threadIdx.x, lane = tid & 63, wv = tid >> 6;
  int t = blockIdx.x * 4 + wv;
  const float* xr = x + (long)t * DD;
  float acc[EE] = {0,0,0,0,0,0,0,0};
  float c0 = 0.0f, c1 = 0.0f;
  for (int d = lane; d < DD; d += 64) {
    float xv = xr[d];
#pragma unroll
    for (int e = 0; e < EE; ++e) acc[e] += xv * wg[d * EE + e];
    c0 += xv * cw[d * 2 + 0];
    c1 += xv * cw[d * 2 + 1];
  }
#pragma unroll
  for (int o = 32; o > 0; o >>= 1) {
#pragma unroll
    for (int e = 0; e < EE; ++e) acc[e] += __shfl_xor(acc[e], o);
    c0 += __shfl_xor(c0, o);
    c1 += __shfl_xor(c1, o);
  }
  __shared__ float sme[EE];
  if (tid < EE) sme[tid] = 0.0f;
  __syncthreads();
  if (lane == 0) {
    float m = acc[0]; int am = 0;
#pragma unroll
    for (int e = 1; e < EE; ++e) if (acc[e] > m) { m = acc[e]; am = e; }
    float g[EE]; float s = 0.0f;
#pragma unroll
    for (int e = 0; e < EE; ++e) { g[e] = __expf(acc[e] - m); s += g[e]; }
    float inv = 1.0f / s;
    idx[t] = am;
    gatev[t] = g[am] * inv;
#pragma unroll
    for (int e = 0; e < EE; ++e) atomicAdd(&sme[e], g[e] * inv);
    float l0 = c0 + cbv[0], l1 = c1 + cbv[1];
    float mm = fmaxf(l0, l1);
    float e0 = __expf(l0 - mm), e1 = __expf(l1 - mm);
    float is = 1.0f / (e0 + e1);
    coef[t * 2 + 0] = e0 * is;
    coef[t * 2 + 1] = e1 * is;
  }
  __syncthreads();
  if (tid < EE) atomicAdd(&me_sum[tid], sme[tid]);
}

// ---------------- capacity scan ----------------
__global__ void scan_k(const int* __restrict__ idx, const float* __restrict__ me_sum,
                       int* __restrict__ slot, int* __restrict__ tok,
                       float* __restrict__ out_tail) {
  __shared__ int sidx[T_TOK];
  __shared__ int counts[EE];
  int tid = threadIdx.x;
  for (int i = tid; i < T_TOK; i += 512) sidx[i] = idx[i];
  __syncthreads();
  int e = tid >> 6, lane = tid & 63;
  int base = 0;
  for (int it = 0; it < T_TOK / 64; ++it) {
    int t = it * 64 + lane;
    bool f = (sidx[t] == e);
    unsigned long long m = __ballot(f);
    if (f) {
      int loc = base + __popcll(m & ((1ull << lane) - 1ull));
      slot[t] = (loc < CC) ? loc : -1;
      if (loc < CC) tok[e * CC + loc] = t;
    }
    base += __popcll(m);
  }
  if (lane == 0) counts[e] = base;
  __syncthreads();
  int filled = min(counts[e], CC);
  for (int c = filled + lane; c < CC; c += 64) tok[e * CC + c] = -1;
  if (tid == 0) {
    float la = 0.0f;
    for (int i = 0; i < EE; ++i) la += me_sum[i] * (float)counts[i];
    la *= (float)EE / ((float)T_TOK * (float)T_TOK);
    out_tail[0] = la;
    for (int i = 0; i < EE; ++i) out_tail[1 + i] = (float)counts[i];
  }
}

// ---------------- gather + bf16 convert ----------------
__global__ void gather_k(const float* __restrict__ x, const int* __restrict__ tok,
                         unsigned short* __restrict__ xb, unsigned short* __restrict__ xe) {
  int r = blockIdx.x, tid = threadIdx.x;
  int d = tid * 4;
  if (r < T_TOK) {
    float4 v = *(const float4*)(x + (long)r * DD + d);
    us4 o; o.x = f2bf(v.x); o.y = f2bf(v.y); o.z = f2bf(v.z); o.w = f2bf(v.w);
    *(us4*)(xb + (long)r * DD + d) = o;
  } else {
    int s = r - T_TOK;
    int t = tok[s];
    us4 o = {0, 0, 0, 0};
    if (t >= 0) {
      float4 v = *(const float4*)(x + (long)t * DD + d);
      o.x = f2bf(v.x); o.y = f2bf(v.y); o.z = f2bf(v.z); o.w = f2bf(v.w);
    }
    *(us4*)(xe + (long)s * DD + d) = o;
  }
}

// ---------------- GEMM1: H = silu(A@W1)*(A@W3), direct-f32 B -----
// Round-10 proven structure (3 bufs, vmcnt(6), chunk-permuted f32 B rows,
// 8x ds_read_b32 + v_cvt_pk per frag), rebalanced waves wm2 x wn4:
// wave tile 128m x 32n-dual cuts block LDS-read volume 160->128 KB/half
// (B f32 is 2x the bytes of A bf16, so wn-heavy partition is optimal).
__global__ __launch_bounds__(512, 2)
void gemm1_k(const unsigned short* __restrict__ xcat,
             const float* __restrict__ w1, const float* __restrict__ w3,
             const float* __restrict__ rw1, const float* __restrict__ rw3,
             unsigned short* __restrict__ Hcat) {
  int lin = blockIdx.x;
  int work = (lin & 7) * 88 + (lin >> 3);     // 704 = 8 * 88
  int mtile, ntile;
  if (work < 352) {            // experts: B-panel-sharing mtile pair adjacent
    int e = work / 44, r = work - e * 44;
    ntile = r >> 1;
    mtile = e * 2 + (r & 1);
  } else {                     // residual: 16 consecutive share B panel
    int q = work - 352;
    ntile = q >> 4;
    mtile = 16 + (q & 15);
  }
  const unsigned short* A = xcat + (size_t)mtile * 256 * DD;
  const float *B1, *B3;
  if (mtile < 16) { int e = mtile >> 1; B1 = w1 + (size_t)e * DD * FF; B3 = w3 + (size_t)e * DD * FF; }
  else { B1 = rw1; B3 = rw3; }
  unsigned short* H = Hcat + (size_t)mtile * 256 * FF;
  int n0 = ntile * 128;

  __shared__ __align__(16) char Lc[147456];   // 144 KB
  const unsigned short* ldsS = (const unsigned short*)Lc;
  // A:  3 bufs x 16KB  [0..49152)       buf*16384 + frag16*1024
  // B1: 3 bufs x 16KB  [49152..98304)   f32 rows: k*512B, chunk-permuted
  // B3: 3 bufs x 16KB  [98304..147456)

  int tid = threadIdx.x, l = tid & 63, w = tid >> 6;
  int wm = w >> 2, wn = w & 3;               // wm2 x wn4
  int fr = l & 15, fq = l >> 4;
  int srow = l >> 2, soff = STG_CHUNK(l);
  int rdo = RD_OFF(fr, fq);

  // A staging sources (bf16, unchanged)
  const unsigned short* gA0 = A + (size_t)(w * 16 + srow) * DD + soff;
  const unsigned short* gA1 = A + (size_t)((8 + w) * 16 + srow) * DD + soff;
  // B staging sources (f32): glds g covers rows 2*(8g+w)..+1 of the 32-row half
  int lrow = l >> 5;                  // 0..1
  int kl0 = 2 * w + lrow;             // rows 0..15
  int kl1 = 16 + 2 * w + lrow;        // rows 16..31
  int cs0 = (l & 31) ^ (((kl0 >> 3) & 1) << 2);
  int cs1 = (l & 31) ^ (((kl1 >> 3) & 1) << 2);
  int nn0 = n0 + 4 * cs0; if (nn0 >= FF) nn0 = 0;   // clamp OOB (masked cols)
  int nn1 = n0 + 4 * cs1; if (nn1 >= FF) nn1 = 0;
  const float* gB1a = B1 + (size_t)kl0 * FF + nn0;
  const float* gB1b = B1 + (size_t)kl1 * FF + nn1;
  const float* gB3a = B3 + (size_t)kl0 * FF + nn0;
  const float* gB3b = B3 + (size_t)kl1 * FF + nn1;

  // per-lane B read column bases (byte): fq*4096 + swizzled column
  int cb[2];
#pragma unroll
  for (int ni = 0; ni < 2; ++ni)
    cb[ni] = fq * 4096 + ((((wn * 2 + ni) * 64 + fr * 4)) ^ ((fq & 1) << 6));

#define STG1(bb, hw) do { size_t ka = (size_t)(hw) * 32; size_t kb = ka * FF;   \
    GLDS16(gA0 + ka, Lc + (bb) * 16384 + w * 1024);                             \
    GLDS16(gA1 + ka, Lc + (bb) * 16384 + (8 + w) * 1024);                       \
    GLDS16(gB1a + kb, Lc + 49152 + (bb) * 16384 + w * 1024);                    \
    GLDS16(gB1b + kb, Lc + 49152 + (bb) * 16384 + (8 + w) * 1024);              \
    GLDS16(gB3a + kb, Lc + 98304 + (bb) * 16384 + w * 1024);                    \
    GLDS16(gB3b + kb, Lc + 98304 + (bb) * 16384 + (8 + w) * 1024); } while (0)

  f32x4 acc1[8][2] = {};
  f32x4 acc3[8][2] = {};

  const int HN = 32;   // K halves (1024/32)
  STG1(0, 0);
  STG1(1, 1);

  for (int h = 0; h < HN; ++h) {
    int buf = h % 3;
    int hw = h + 2; if (hw >= HN) hw -= HN;
    int bufw = (buf + 2) % 3;

    asm volatile("s_waitcnt vmcnt(6)" ::: "memory");   // half h landed
    BAR();                                             // all waves see it; WAR safe
    STG1(bufw, hw);                                    // prefetch h+2 (overlaps compute)

    const char* Bb1 = Lc + 49152 + buf * 16384;
    const char* Bb3 = Lc + 98304 + buf * 16384;
    bf16x8 af[8];
#pragma unroll
    for (int mi = 0; mi < 8; ++mi)
      af[mi] = *(const bf16x8*)(ldsS + buf * 8192 + (wm * 8 + mi) * 512 + rdo);

    // ---- B1 phase -> acc1 ----
    {
      float fb[2][8];
#pragma unroll
      for (int ni = 0; ni < 2; ++ni)
#pragma unroll
        for (int j = 0; j < 8; ++j)
          fb[ni][j] = *(const float*)(Bb1 + cb[ni] + j * 512);
      __builtin_amdgcn_s_setprio(1);
#pragma unroll
      for (int ni = 0; ni < 2; ++ni) {
        union { bf16x8 h; unsigned int u[4]; } bu;
#pragma unroll
        for (int p = 0; p < 4; ++p)
          asm("v_cvt_pk_bf16_f32 %0, %1, %2" : "=v"(bu.u[p]) : "v"(fb[ni][2 * p]), "v"(fb[ni][2 * p + 1]));
#pragma unroll
        for (int mi = 0; mi < 8; ++mi)
          acc1[mi][ni] = __builtin_amdgcn_mfma_f32_16x16x32_bf16(af[mi], bu.h, acc1[mi][ni], 0, 0, 0);
      }
      __builtin_amdgcn_s_setprio(0);
    }
    // ---- B3 phase -> acc3 ----
    {
      float fb[2][8];
#pragma unroll
      for (int ni = 0; ni < 2; ++ni)
#pragma unroll
        for (int j = 0; j < 8; ++j)
          fb[ni][j] = *(const float*)(Bb3 + cb[ni] + j * 512);
      __builtin_amdgcn_s_setprio(1);
#pragma unroll
      for (int ni = 0; ni < 2; ++ni) {
        union { bf16x8 h; unsigned int u[4]; } bu;
#pragma unroll
        for (int p = 0; p < 4; ++p)
          asm("v_cvt_pk_bf16_f32 %0, %1, %2" : "=v"(bu.u[p]) : "v"(fb[ni][2 * p]), "v"(fb[ni][2 * p + 1]));
#pragma unroll
        for (int mi = 0; mi < 8; ++mi)
          acc3[mi][ni] = __builtin_amdgcn_mfma_f32_16x16x32_bf16(af[mi], bu.h, acc3[mi][ni], 0, 0, 0);
      }
      __builtin_amdgcn_s_setprio(0);
    }
  }
#undef STG1

#pragma unroll
  for (int mi = 0; mi < 8; ++mi)
#pragma unroll
    for (int ni = 0; ni < 2; ++ni)
#pragma unroll
      for (int r = 0; r < 4; ++r) {
        int gm = wm * 128 + mi * 16 + fq * 4 + r;
        int gn = n0 + (wn * 2 + ni) * 16 + fr;
        if (gn < FF) {
          float v1 = acc1[mi][ni][r], v3 = acc3[mi][ni][r];
          float h = v1 / (1.0f + __expf(-v1)) * v3;
          H[(size_t)gm * FF + gn] = f2bf(h);
        }
      }
}

// ---------------- GEMM2: Y = H @ W2 (round-9/10 verified) --------
__global__ __launch_bounds__(512, 2)
void gemm2_k(const unsigned short* __restrict__ Hcat,
             const unsigned short* __restrict__ w2t, const unsigned short* __restrict__ rw2t,
             unsigned short* __restrict__ Ycat) {
  int lin = blockIdx.x;
  int work = (lin & 7) * 32 + (lin >> 3);    // 256 = 8 * 32
  int mtile, ntile;
  if (work < 128) {
    int e = work >> 4, r = work & 15;
    ntile = r >> 1;
    mtile = e * 2 + (r & 1);
  } else {
    int q = work - 128;
    ntile = q >> 4;
    mtile = 16 + (q & 15);
  }
  const unsigned short* A = Hcat + (size_t)mtile * 256 * FF;
  const unsigned short* B = (mtile < 16) ? (w2t + (size_t)(mtile >> 1) * (size_t)DD * FF) : rw2t;
  unsigned short* Y = Ycat + (size_t)mtile * 256 * DD;
  int n0 = ntile * 128;

  __shared__ __align__(16) unsigned short lds[73728];   // 144 KB
  char* Lc = (char*)lds;

  int tid = threadIdx.x, l = tid & 63, w = tid >> 6;
  int wm = w >> 1, wn = w & 1;
  int fr = l & 15, fq = l >> 4;
  int srow = l >> 2, soff = STG_CHUNK(l);
  int rdo = RD_OFF(fr, fq);

  const unsigned short* gA0 = A + (size_t)(w * 16 + srow) * FF + soff;
  const unsigned short* gA1 = A + (size_t)((8 + w) * 16 + srow) * FF + soff;
  const unsigned short* gB  = B + (size_t)(n0 + w * 16 + srow) * FF + soff;

#define STG2(bb, kk) do {                                          \
    GLDS16(gA0 + (kk), Lc + (bb) * 16384 + w * 1024);              \
    GLDS16(gA1 + (kk), Lc + (bb) * 16384 + (8 + w) * 1024);        \
    GLDS16(gB  + (kk), Lc + 98304 + (bb) * 8192 + w * 1024); } while (0)

  f32x4 acc[4][4] = {};

  const int HN = 86;   // halves (K=2752 / 32)
#pragma unroll
  for (int hh = 0; hh < 5; ++hh) STG2(hh, hh * 32);
  asm volatile("s_waitcnt vmcnt(12)" ::: "memory");
  BAR();

  int b = 0;
#pragma unroll 2
  for (int h = 0; h < HN; ++h) {
    int bn = b ? b - 1 : 5;              // (h+5) % 6
    int hw = h + 5; if (hw >= HN) hw -= HN;
    int kk = hw * 32;
    bf16x8 af[4], bf[4];

#pragma unroll
    for (int mi = 0; mi < 4; ++mi)
      af[mi] = *(const bf16x8*)(lds + b * 8192 + (wm * 4 + mi) * 512 + rdo);
#pragma unroll
    for (int ni = 0; ni < 4; ++ni)
      bf[ni] = *(const bf16x8*)(lds + 49152 + b * 4096 + (wn * 4 + ni) * 512 + rdo);
    STG2(bn, kk);
    asm volatile("s_waitcnt vmcnt(12)" ::: "memory");
    BAR();
    __builtin_amdgcn_s_setprio(1);
#pragma unroll
    for (int mi = 0; mi < 4; ++mi)
#pragma unroll
      for (int ni = 0; ni < 4; ++ni)
        acc[mi][ni] = __builtin_amdgcn_mfma_f32_16x16x32_bf16(af[mi], bf[ni], acc[mi][ni], 0, 0, 0);
    __builtin_amdgcn_s_setprio(0);
    BAR();

    ++b; if (b == 6) b = 0;
  }
#undef STG2

#pragma unroll
  for (int mi = 0; mi < 4; ++mi)
#pragma unroll
    for (int ni = 0; ni < 4; ++ni)
#pragma unroll
      for (int r = 0; r < 4; ++r) {
        int gm = wm * 64 + mi * 16 + fq * 4 + r;
        int gn = n0 + wn * 64 + ni * 16 + fr;
        Y[(size_t)gm * DD + gn] = f2bf(acc[mi][ni][r]);
      }
}

// ---------------- combine ----------------------------------------
__global__ void combine_k(const unsigned short* __restrict__ Ye, const unsigned short* __restrict__ Yr,
                          const int* __restrict__ idx, const int* __restrict__ slot,
                          const float* __restrict__ gatev, const float* __restrict__ coef,
                          float* __restrict__ out) {
  int t = blockIdx.x, tid = threadIdx.x;
  int d = tid * 4;
  float c0 = coef[t * 2], c1 = coef[t * 2 + 1];
  int s = slot[t];
  float g = gatev[t] * c0;
  us4 vr = *(const us4*)(Yr + (size_t)t * DD + d);
  float4 o;
  if (s >= 0) {
    us4 ve = *(const us4*)(Ye + ((size_t)idx[t] * CC + s) * DD + d);
    o.x = g * bf2f(ve.x) + c1 * bf2f(vr.x);
    o.y = g * bf2f(ve.y) + c1 * bf2f(vr.y);
    o.z = g * bf2f(ve.z) + c1 * bf2f(vr.z);
    o.w = g * bf2f(ve.w) + c1 * bf2f(vr.w);
  } else {
    o.x = c1 * bf2f(vr.x);
    o.y = c1 * bf2f(vr.y);
    o.z = c1 * bf2f(vr.z);
    o.w = c1 * bf2f(vr.w);
  }
  *(float4*)(out + (size_t)t * DD + d) = o;
}

// ---------------- launch -----------------------------------------
extern "C" void kernel_launch(void* const* d_in, const int* in_sizes, int n_in,
                              void* d_out, int out_size, void* d_ws, size_t ws_size,
                              hipStream_t stream) {
  const float* x   = (const float*)d_in[0];
  const float* wg  = (const float*)d_in[1];
  const float* w1  = (const float*)d_in[2];
  const float* w3  = (const float*)d_in[3];
  const float* w2  = (const float*)d_in[4];
  const float* rw1 = (const float*)d_in[5];
  const float* rw3 = (const float*)d_in[6];
  const float* rw2 = (const float*)d_in[7];
  const float* cw  = (const float*)d_in[8];
  const float* cbv = (const float*)d_in[9];
  float* out = (float*)d_out;

  char* ws = (char*)d_ws;
  size_t o = 0;
  auto alloc = [&](size_t bytes) -> char* {
    char* p = ws + o; o = (o + bytes + 255) & ~(size_t)255; return p;
  };
  unsigned short* w2t  = (unsigned short*)alloc((size_t)EE * DD * FF * 2);
  unsigned short* rw2t = (unsigned short*)alloc((size_t)DD * FF * 2);
  // contiguous pairs: xe|xb, He|Hr, Ye|Yr
  unsigned short* xe   = (unsigned short*)alloc((size_t)T_TOK * DD * 2);
  unsigned short* xb   = (unsigned short*)alloc((size_t)T_TOK * DD * 2);
  unsigned short* He   = (unsigned short*)alloc((size_t)T_TOK * FF * 2);
  unsigned short* Hr   = (unsigned short*)alloc((size_t)T_TOK * FF * 2);
  unsigned short* Ye   = (unsigned short*)alloc((size_t)T_TOK * DD * 2);
  unsigned short* Yr   = (unsigned short*)alloc((size_t)T_TOK * DD * 2);
  int*   idxp  = (int*)alloc(T_TOK * 4);
  float* gatev = (float*)alloc(T_TOK * 4);
  int*   slotp = (int*)alloc(T_TOK * 4);
  int*   tokp  = (int*)alloc(EE * CC * 4);
  float* coefp = (float*)alloc(T_TOK * 2 * 4);
  float* mep   = (float*)alloc(256);
  if (o > ws_size) return;

  // only w2 needs the transpose+convert pre-pass
  transpose_k<64><<<dim3(16, 43, EE + 1), 256, 0, stream>>>(w2, rw2, w2t, rw2t, FF, DD, (long)FF * DD, (long)DD * FF);

  zero_me_k<<<1, 64, 0, stream>>>(mep);
  gate_k<<<T_TOK / 4, 256, 0, stream>>>(x, wg, cw, cbv, idxp, gatev, coefp, mep);
  scan_k<<<1, 512, 0, stream>>>(idxp, mep, slotp, tokp, out + (size_t)T_TOK * DD);
  gather_k<<<2 * T_TOK, 256, 0, stream>>>(x, tokp, xb, xe);
  gemm1_k<<<704, 512, 0, stream>>>(xe, w1, w3, rw1, rw3, He);
  gemm2_k<<<256, 512, 0, stream>>>(He, w2t, rw2t, Ye);
  combine_k<<<T_TOK, 256, 0, stream>>>(Ye, Yr, idxp, slotp, gatev, coefp, out);
}